// Round 6
// baseline (1108.041 us; speedup 1.0000x reference)
//
#include <hip/hip_runtime.h>
#include <cfloat>
#include <cmath>
#include <cstdint>

#define N_TOK 65536
#define N_E   2048
#define E_DIM 256
#define BETA  0.25

#define MGN 2.5e-4f   // candidate margin (worst-case need ~1.2e-4)
#define CMAX 16

// ws layout (bytes)
#define WS_LOSSPART 0          // double[2048]    -> 16384
#define WS_A        16384      // float[65536]    -> 278528
#define WS_B        278528     // float[2048]     -> 286720
#define WS_IDXF     286720     // int[65536]      -> 548864
#define WS_COUNTS   548864     // int[2048]       -> 557056
#define WS_EH       557056     // ushort[524288]  -> 1605632
#define WS_EL       1605632    // ushort[524288]  -> 2654208
#define WS_CCNT     2654208    // int[65536]      -> 2916352
#define WS_CAND     2916352    // ushort[65536*16]-> 5013504

typedef __attribute__((ext_vector_type(8))) short short8v;
typedef __attribute__((ext_vector_type(4))) float f32x4;

__device__ __forceinline__ ushort f2bf(float f) {
  union { float f; uint32_t u; } v; v.f = f;
  const uint32_t r = v.u + 0x7FFFu + ((v.u >> 16) & 1u);
  return (ushort)(r >> 16);
}
__device__ __forceinline__ float bf2f(ushort h) {
  union { uint32_t u; float f; } v; v.u = (uint32_t)h << 16;
  return v.f;
}

// exact sequential fused-FMA chain (verified bit-exact vs numpy sgemm, R3)
__device__ __forceinline__ float chain_m(const float* __restrict__ zp,
                                         const float* __restrict__ ep) {
  float acc = 0.f;
  for (int k = 0; k < E_DIM; k += 4) {
    const float4 zz = *(const float4*)(zp + k);
    const float4 ee = *(const float4*)(ep + k);
    acc = __fmaf_rn(zz.x, ee.x, acc);
    acc = __fmaf_rn(zz.y, ee.y, acc);
    acc = __fmaf_rn(zz.z, ee.z, acc);
    acc = __fmaf_rn(zz.w, ee.w, acc);
  }
  return acc;
}

// ---------------------------------------------------------------------------
// numpy f32 pairwise sum of squares (verified bit-exact, R3)
// ---------------------------------------------------------------------------
__device__ __forceinline__ float np_sq_pairwise256(const float* __restrict__ x) {
  float blk[2];
#pragma unroll
  for (int h = 0; h < 2; ++h) {
    const float* p = x + h * 128;
    float lane[16];
#pragma unroll
    for (int l = 0; l < 16; ++l) {
      const float q0 = __fmul_rn(p[l +   0], p[l +   0]);
      const float q1 = __fmul_rn(p[l +  16], p[l +  16]);
      const float q2 = __fmul_rn(p[l +  32], p[l +  32]);
      const float q3 = __fmul_rn(p[l +  48], p[l +  48]);
      const float q4 = __fmul_rn(p[l +  64], p[l +  64]);
      const float q5 = __fmul_rn(p[l +  80], p[l +  80]);
      const float q6 = __fmul_rn(p[l +  96], p[l +  96]);
      const float q7 = __fmul_rn(p[l + 112], p[l + 112]);
      lane[l] = __fadd_rn(__fadd_rn(__fadd_rn(q0, q1), __fadd_rn(q2, q3)),
                          __fadd_rn(__fadd_rn(q4, q5), __fadd_rn(q6, q7)));
    }
    float u[8];
#pragma unroll
    for (int l = 0; l < 8; ++l) u[l] = __fadd_rn(lane[l], lane[l + 8]);
    float v[4];
#pragma unroll
    for (int l = 0; l < 4; ++l) v[l] = __fadd_rn(u[l], u[l + 4]);
    const float w0 = __fadd_rn(v[0], v[2]);
    const float w1 = __fadd_rn(v[1], v[3]);
    blk[h] = __fadd_rn(w0, w1);
  }
  return __fadd_rn(blk[0], blk[1]);
}

__global__ __launch_bounds__(256) void k_ab(const float* __restrict__ z,
                                            const float* __restrict__ E,
                                            float* __restrict__ a,
                                            float* __restrict__ b) {
  const int r = blockIdx.x * 256 + threadIdx.x;
  if (r < N_TOK) {
    a[r] = np_sq_pairwise256(z + (size_t)r * E_DIM);
  } else {
    const int e = r - N_TOK;
    if (e < N_E) b[e] = np_sq_pairwise256(E + (size_t)e * E_DIM);
  }
}

__global__ void k_zero(int* __restrict__ counts) {
  const int i = blockIdx.x * 256 + threadIdx.x;
  if (i < N_E) counts[i] = 0;
}

// split f32 -> bf16 hi + bf16 lo (RNE both)
__global__ __launch_bounds__(256) void k_split(const float* __restrict__ x,
                                               ushort* __restrict__ hi,
                                               ushort* __restrict__ lo,
                                               int n4) {
  const int i = blockIdx.x * 256 + threadIdx.x;
  if (i >= n4) return;
  const float4 v = *(const float4*)&x[(size_t)i * 4];
  ushort4 h, w;
  h.x = f2bf(v.x); w.x = f2bf(__fsub_rn(v.x, bf2f(h.x)));
  h.y = f2bf(v.y); w.y = f2bf(__fsub_rn(v.y, bf2f(h.y)));
  h.z = f2bf(v.z); w.z = f2bf(__fsub_rn(v.z, bf2f(h.z)));
  h.w = f2bf(v.w); w.w = f2bf(__fsub_rn(v.w, bf2f(h.w)));
  *(ushort4*)&hi[(size_t)i * 4] = h;
  *(ushort4*)&lo[(size_t)i * 4] = w;
}

// ---------------------------------------------------------------------------
// MFMA filter: s~ = b - 2*(zh*eh + zh*el + zl*eh), per-token running min +
// candidate collection within MGN. 128 tokens/block (8 waves x 16 tokens),
// all 2048 codes per block in 16-code tiles.
// ---------------------------------------------------------------------------
__global__ __launch_bounds__(512) void k_mfma(
    const ushort* __restrict__ zh, const ushort* __restrict__ zl,
    const ushort* __restrict__ eh, const ushort* __restrict__ el,
    const float* __restrict__ b, int* __restrict__ gcnt,
    ushort* __restrict__ gcand) {
  __shared__ int s_cnt[128];
  __shared__ ushort s_idx[128][CMAX];
  __shared__ float s_val[128][CMAX];
  __shared__ float s_rmin[128];

  const int tid = threadIdx.x;
  const int wv = tid >> 6;       // wave 0..7
  const int l = tid & 63;
  const int c16 = l & 15;        // A-row / B-col / D-col lane index
  const int kb = l >> 4;         // k-subchunk 0..3
  const int tokBase = blockIdx.x * 128 + wv * 16;

  if (tid < 128) s_cnt[tid] = 0;
  __syncthreads();

  // A fragments (hi/lo) for this wave's 16 tokens, all K=256 (8 chunks of 32)
  short8v Ah[8], Al[8];
  {
    const ushort* zhp = zh + (size_t)(tokBase + c16) * E_DIM + kb * 8;
    const ushort* zlp = zl + (size_t)(tokBase + c16) * E_DIM + kb * 8;
#pragma unroll
    for (int kk = 0; kk < 8; ++kk) {
      Ah[kk] = *(const short8v*)(zhp + kk * 32);
      Al[kk] = *(const short8v*)(zlp + kk * 32);
    }
  }

  float runmin[4] = {FLT_MAX, FLT_MAX, FLT_MAX, FLT_MAX};

  for (int ct = 0; ct < N_E / 16; ++ct) {
    const int c0 = ct * 16;
    const ushort* ehp = eh + (size_t)(c0 + c16) * E_DIM + kb * 8;
    const ushort* elp = el + (size_t)(c0 + c16) * E_DIM + kb * 8;
    f32x4 acc = {0.f, 0.f, 0.f, 0.f};
#pragma unroll
    for (int kk = 0; kk < 8; ++kk) {
      const short8v Bh = *(const short8v*)(ehp + kk * 32);
      const short8v Bl = *(const short8v*)(elp + kk * 32);
      acc = __builtin_amdgcn_mfma_f32_16x16x32_bf16(Al[kk], Bh, acc, 0, 0, 0);
      acc = __builtin_amdgcn_mfma_f32_16x16x32_bf16(Ah[kk], Bl, acc, 0, 0, 0);
      acc = __builtin_amdgcn_mfma_f32_16x16x32_bf16(Ah[kk], Bh, acc, 0, 0, 0);
    }
    // lane holds m~ for D[row=kb*4+r][col=c0+c16]
    const float bc = b[c0 + c16];
    float sv[4];
#pragma unroll
    for (int r = 0; r < 4; ++r) sv[r] = bc - 2.f * acc[r];
    float tm[4] = {sv[0], sv[1], sv[2], sv[3]};
#pragma unroll
    for (int m = 1; m < 16; m <<= 1)
#pragma unroll
      for (int r = 0; r < 4; ++r) tm[r] = fminf(tm[r], __shfl_xor(tm[r], m, 64));
#pragma unroll
    for (int r = 0; r < 4; ++r) {
      const float thr = fminf(runmin[r], tm[r]) + MGN;
      if (sv[r] <= thr) {
        const int tokl = wv * 16 + kb * 4 + r;
        const int p = atomicAdd(&s_cnt[tokl], 1);
        if (p < CMAX) {
          s_idx[tokl][p] = (ushort)(c0 + c16);
          s_val[tokl][p] = sv[r];
        }
      }
      runmin[r] = fminf(runmin[r], tm[r]);
    }
  }

  if (c16 == 0) {
#pragma unroll
    for (int r = 0; r < 4; ++r) s_rmin[wv * 16 + kb * 4 + r] = runmin[r];
  }
  __syncthreads();

  // final refilter against the global min, write lists
  if (tid < 128) {
    const int t = blockIdx.x * 128 + tid;
    const int cnt = s_cnt[tid];
    if (cnt > CMAX) {
      gcnt[t] = 1000;  // overflow sentinel -> full-scan fallback
    } else {
      const float thr = s_rmin[tid] + MGN;
      int nk = 0;
      for (int p = 0; p < cnt; ++p)
        if (s_val[tid][p] <= thr) gcand[(size_t)t * CMAX + nk++] = s_idx[tid][p];
      gcnt[t] = nk;
    }
  }
}

// exact chain re-evaluation of candidates, lexicographic (D, idx) pick
__global__ __launch_bounds__(256) void k_refine(
    const float* __restrict__ z, const float* __restrict__ E,
    const float* __restrict__ a, const float* __restrict__ b,
    const int* __restrict__ gcnt, const ushort* __restrict__ gcand,
    int* __restrict__ idxF, float* __restrict__ out_idx) {
  const int t = blockIdx.x * 256 + threadIdx.x;
  if (t >= N_TOK) return;
  const int cnt = gcnt[t];
  if (cnt > CMAX) return;  // fallback kernel handles
  int bestj;
  if (cnt == 1) {
    bestj = gcand[(size_t)t * CMAX];
  } else {
    float bv = FLT_MAX;
    int bj = 1 << 30;
    const float* zp = z + (size_t)t * E_DIM;
    for (int p = 0; p < cnt; ++p) {
      const int c = gcand[(size_t)t * CMAX + p];
      const float m = chain_m(zp, E + (size_t)c * E_DIM);
      const float D = __fsub_rn(__fadd_rn(a[t], b[c]), __fmul_rn(2.0f, m));
      if (D < bv || (D == bv && c < bj)) { bv = D; bj = c; }
    }
    bestj = bj;
  }
  idxF[t] = bestj;
  out_idx[t] = (float)bestj;
}

// cooperative full scan for overflow tokens (rare)
__global__ __launch_bounds__(256) void k_fallback(
    const float* __restrict__ z, const float* __restrict__ E,
    const float* __restrict__ a, const float* __restrict__ b,
    const int* __restrict__ gcnt, int* __restrict__ idxF,
    float* __restrict__ out_idx) {
  __shared__ float rv[256];
  __shared__ int ri[256];
  const int t0 = blockIdx.x * 64;
  for (int t = t0; t < t0 + 64; ++t) {
    if (gcnt[t] <= CMAX) continue;  // uniform across block
    const float* zp = z + (size_t)t * E_DIM;
    float bv = FLT_MAX;
    int bj = 1 << 30;
    for (int c = threadIdx.x; c < N_E; c += 256) {
      const float m = chain_m(zp, E + (size_t)c * E_DIM);
      const float D = __fsub_rn(__fadd_rn(a[t], b[c]), __fmul_rn(2.0f, m));
      if (D < bv || (D == bv && c < bj)) { bv = D; bj = c; }
    }
    rv[threadIdx.x] = bv;
    ri[threadIdx.x] = bj;
    __syncthreads();
    for (int s = 128; s; s >>= 1) {
      if (threadIdx.x < s) {
        const float ov = rv[threadIdx.x + s];
        const int oj = ri[threadIdx.x + s];
        if (ov < rv[threadIdx.x] ||
            (ov == rv[threadIdx.x] && oj < ri[threadIdx.x])) {
          rv[threadIdx.x] = ov;
          ri[threadIdx.x] = oj;
        }
      }
      __syncthreads();
    }
    if (threadIdx.x == 0) { idxF[t] = ri[0]; out_idx[t] = (float)ri[0]; }
    __syncthreads();
  }
}

// gather z_q, write z_q_st = fl(z + fl(zq - z)), accumulate f64 loss partials
__global__ __launch_bounds__(256) void k_gather(
    const float* __restrict__ z, const float* __restrict__ E,
    const int* __restrict__ idxF, float* __restrict__ out0,
    double* __restrict__ lossPart) {
  double ls = 0.0;
  const int NU = N_TOK * (E_DIM / 4);
  for (int u = blockIdx.x * 256 + threadIdx.x; u < NU; u += 2048 * 256) {
    const int tok = u >> 6;
    const int d4 = (u & 63) * 4;
    const int c = idxF[tok];
    const float4 zq = *(const float4*)&E[(size_t)c * E_DIM + d4];
    const float4 zv = *(const float4*)&z[(size_t)tok * E_DIM + d4];
    float4 o;
    o.x = __fadd_rn(zv.x, __fsub_rn(zq.x, zv.x));
    o.y = __fadd_rn(zv.y, __fsub_rn(zq.y, zv.y));
    o.z = __fadd_rn(zv.z, __fsub_rn(zq.z, zv.z));
    o.w = __fadd_rn(zv.w, __fsub_rn(zq.w, zv.w));
    *(float4*)&out0[(size_t)u * 4] = o;
    double dx;
    dx = (double)zq.x - (double)zv.x; ls += dx * dx;
    dx = (double)zq.y - (double)zv.y; ls += dx * dx;
    dx = (double)zq.z - (double)zv.z; ls += dx * dx;
    dx = (double)zq.w - (double)zv.w; ls += dx * dx;
  }
  __shared__ double red[256];
  red[threadIdx.x] = ls;
  __syncthreads();
  for (int s = 128; s; s >>= 1) {
    if (threadIdx.x < s) red[threadIdx.x] += red[threadIdx.x + s];
    __syncthreads();
  }
  if (threadIdx.x == 0) lossPart[blockIdx.x] = red[0];
}

__global__ __launch_bounds__(256) void k_hist(const int* __restrict__ idxF,
                                              int* __restrict__ counts) {
  const int t = blockIdx.x * 256 + threadIdx.x;
  atomicAdd(&counts[idxF[t]], 1);
}

__global__ __launch_bounds__(256) void k_final(
    const double* __restrict__ lossPart, const int* __restrict__ counts,
    float* __restrict__ outLoss, float* __restrict__ outPerp) {
  __shared__ double rs[256], rh[256];
  double s = 0.0, h = 0.0;
  for (int j = threadIdx.x; j < 2048; j += 256) s += lossPart[j];
  for (int j = threadIdx.x; j < N_E; j += 256) {
    const double p = (double)counts[j] * (1.0 / (double)N_TOK);
    h -= p * log(p + 1e-10);
  }
  rs[threadIdx.x] = s;
  rh[threadIdx.x] = h;
  __syncthreads();
  for (int m = 128; m; m >>= 1) {
    if (threadIdx.x < m) {
      rs[threadIdx.x] += rs[threadIdx.x + m];
      rh[threadIdx.x] += rh[threadIdx.x + m];
    }
    __syncthreads();
  }
  if (threadIdx.x == 0) {
    outLoss[0] = (float)((1.0 + BETA) * rs[0] / (double)((size_t)N_TOK * E_DIM));
    outPerp[0] = (float)exp(rh[0]);
  }
}

extern "C" void kernel_launch(void* const* d_in, const int* in_sizes, int n_in,
                              void* d_out, int out_size, void* d_ws, size_t ws_size,
                              hipStream_t stream) {
  const float* z = (const float*)d_in[0];
  const float* E = (const float*)d_in[1];

  float* out0 = (float*)d_out;                       // z_q_st [65536*256]
  float* outLoss = out0 + (size_t)N_TOK * E_DIM;
  float* outPerp = outLoss + 1;
  float* outIdx = outPerp + 1;                       // idx as float [65536]

  char* ws = (char*)d_ws;
  double* lossPart = (double*)(ws + WS_LOSSPART);
  float* a = (float*)(ws + WS_A);
  float* b = (float*)(ws + WS_B);
  int* idxF = (int*)(ws + WS_IDXF);
  int* counts = (int*)(ws + WS_COUNTS);
  ushort* eh = (ushort*)(ws + WS_EH);
  ushort* el = (ushort*)(ws + WS_EL);
  int* gcnt = (int*)(ws + WS_CCNT);
  ushort* gcand = (ushort*)(ws + WS_CAND);

  // z splits live in the z_q_st output region (exactly 64 MB); k_gather
  // overwrites it afterwards. Deterministic each call.
  ushort* zh = (ushort*)out0;
  ushort* zl = zh + (size_t)N_TOK * E_DIM;

  hipLaunchKernelGGL(k_zero, dim3(8), dim3(256), 0, stream, counts);
  hipLaunchKernelGGL(k_ab, dim3((N_TOK + N_E) / 256), dim3(256), 0, stream,
                     z, E, a, b);
  hipLaunchKernelGGL(k_split, dim3(N_TOK * E_DIM / 4 / 256), dim3(256), 0,
                     stream, z, zh, zl, N_TOK * E_DIM / 4);
  hipLaunchKernelGGL(k_split, dim3(N_E * E_DIM / 4 / 256), dim3(256), 0,
                     stream, E, eh, el, N_E * E_DIM / 4);
  hipLaunchKernelGGL(k_mfma, dim3(N_TOK / 128), dim3(512), 0, stream,
                     zh, zl, eh, el, b, gcnt, gcand);
  hipLaunchKernelGGL(k_refine, dim3(N_TOK / 256), dim3(256), 0, stream,
                     z, E, a, b, gcnt, gcand, idxF, outIdx);
  hipLaunchKernelGGL(k_fallback, dim3(N_TOK / 64), dim3(256), 0, stream,
                     z, E, a, b, gcnt, idxF, outIdx);
  hipLaunchKernelGGL(k_gather, dim3(2048), dim3(256), 0, stream,
                     z, E, idxF, out0, lossPart);
  hipLaunchKernelGGL(k_hist, dim3(N_TOK / 256), dim3(256), 0, stream, idxF, counts);
  hipLaunchKernelGGL(k_final, dim3(1), dim3(256), 0, stream,
                     lossPart, counts, outLoss, outPerp);
}

// Round 7
// 328.064 us; speedup vs baseline: 3.3775x; 3.3775x over previous
//
#include <hip/hip_runtime.h>
#include <cfloat>
#include <cmath>
#include <cstdint>

#define N_TOK 65536
#define N_E   2048
#define E_DIM 256
#define BETA  0.25

#define MGN 8e-4f     // capture margin; worst-case requirement ~6e-4 (see notes)
#define CMAX 16

// ws layout (bytes)
#define WS_LOSSPART 0          // double[2048]    -> 16384
#define WS_A        16384      // float[65536]    -> 278528
#define WS_B        278528     // float[2048]     -> 286720
#define WS_IDXF     286720     // int[65536]      -> 548864
#define WS_COUNTS   548864     // int[2048]       -> 557056
#define WS_CCNT     2654208    // int[65536]      -> 2916352
#define WS_CAND     2916352    // ushort[65536*16]-> 5013504

typedef __attribute__((ext_vector_type(8))) _Float16 half8;
typedef __attribute__((ext_vector_type(4))) float f32x4;
typedef __attribute__((ext_vector_type(8))) unsigned short ushort8;

__device__ __forceinline__ ushort f2h(float f) {
  union { _Float16 h; ushort u; } c;
  c.h = (_Float16)f;   // RNE
  return c.u;
}

__device__ __forceinline__ void gload_lds16(const void* g, void* l) {
  __builtin_amdgcn_global_load_lds(
      (const __attribute__((address_space(1))) unsigned int*)(g),
      (__attribute__((address_space(3))) unsigned int*)(l), 16, 0, 0);
}

// exact sequential fused-FMA chain (verified bit-exact vs numpy sgemm, R3)
__device__ __forceinline__ float chain_m(const float* __restrict__ zp,
                                         const float* __restrict__ ep) {
  float acc = 0.f;
  for (int k = 0; k < E_DIM; k += 4) {
    const float4 zz = *(const float4*)(zp + k);
    const float4 ee = *(const float4*)(ep + k);
    acc = __fmaf_rn(zz.x, ee.x, acc);
    acc = __fmaf_rn(zz.y, ee.y, acc);
    acc = __fmaf_rn(zz.z, ee.z, acc);
    acc = __fmaf_rn(zz.w, ee.w, acc);
  }
  return acc;
}

// numpy f32 pairwise sum of squares (verified bit-exact, R3)
__device__ __forceinline__ float np_sq_pairwise256(const float* __restrict__ x) {
  float blk[2];
#pragma unroll
  for (int h = 0; h < 2; ++h) {
    const float* p = x + h * 128;
    float lane[16];
#pragma unroll
    for (int l = 0; l < 16; ++l) {
      const float q0 = __fmul_rn(p[l +   0], p[l +   0]);
      const float q1 = __fmul_rn(p[l +  16], p[l +  16]);
      const float q2 = __fmul_rn(p[l +  32], p[l +  32]);
      const float q3 = __fmul_rn(p[l +  48], p[l +  48]);
      const float q4 = __fmul_rn(p[l +  64], p[l +  64]);
      const float q5 = __fmul_rn(p[l +  80], p[l +  80]);
      const float q6 = __fmul_rn(p[l +  96], p[l +  96]);
      const float q7 = __fmul_rn(p[l + 112], p[l + 112]);
      lane[l] = __fadd_rn(__fadd_rn(__fadd_rn(q0, q1), __fadd_rn(q2, q3)),
                          __fadd_rn(__fadd_rn(q4, q5), __fadd_rn(q6, q7)));
    }
    float u[8];
#pragma unroll
    for (int l = 0; l < 8; ++l) u[l] = __fadd_rn(lane[l], lane[l + 8]);
    float v[4];
#pragma unroll
    for (int l = 0; l < 4; ++l) v[l] = __fadd_rn(u[l], u[l + 4]);
    const float w0 = __fadd_rn(v[0], v[2]);
    const float w1 = __fadd_rn(v[1], v[3]);
    blk[h] = __fadd_rn(w0, w1);
  }
  return __fadd_rn(blk[0], blk[1]);
}

__global__ __launch_bounds__(256) void k_ab(const float* __restrict__ z,
                                            const float* __restrict__ E,
                                            float* __restrict__ a,
                                            float* __restrict__ b) {
  const int r = blockIdx.x * 256 + threadIdx.x;
  if (r < N_TOK) {
    a[r] = np_sq_pairwise256(z + (size_t)r * E_DIM);
  } else {
    const int e = r - N_TOK;
    if (e < N_E) b[e] = np_sq_pairwise256(E + (size_t)e * E_DIM);
  }
}

__global__ void k_zero(int* __restrict__ counts) {
  const int i = blockIdx.x * 256 + threadIdx.x;
  if (i < N_E) counts[i] = 0;
}

// z -> fp16 (raw), E -> fp16 scaled by 2048 (exact pow2)
__global__ __launch_bounds__(256) void k_cvt(const float* __restrict__ z,
                                             const float* __restrict__ E,
                                             ushort* __restrict__ zf,
                                             ushort* __restrict__ ef) {
  const int id = blockIdx.x * 256 + threadIdx.x;
  const int NZ8 = N_TOK * E_DIM / 8;
  const int NE8 = N_E * E_DIM / 8;
  if (id < NZ8) {
    const float4 v0 = *(const float4*)&z[(size_t)id * 8];
    const float4 v1 = *(const float4*)&z[(size_t)id * 8 + 4];
    ushort8 o;
    o[0] = f2h(v0.x); o[1] = f2h(v0.y); o[2] = f2h(v0.z); o[3] = f2h(v0.w);
    o[4] = f2h(v1.x); o[5] = f2h(v1.y); o[6] = f2h(v1.z); o[7] = f2h(v1.w);
    *(ushort8*)&zf[(size_t)id * 8] = o;
  } else if (id < NZ8 + NE8) {
    const int ie = id - NZ8;
    const float4 v0 = *(const float4*)&E[(size_t)ie * 8];
    const float4 v1 = *(const float4*)&E[(size_t)ie * 8 + 4];
    ushort8 o;
    o[0] = f2h(v0.x * 2048.0f); o[1] = f2h(v0.y * 2048.0f);
    o[2] = f2h(v0.z * 2048.0f); o[3] = f2h(v0.w * 2048.0f);
    o[4] = f2h(v1.x * 2048.0f); o[5] = f2h(v1.y * 2048.0f);
    o[6] = f2h(v1.z * 2048.0f); o[7] = f2h(v1.w * 2048.0f);
    *(ushort8*)&ef[(size_t)ie * 8] = o;
  }
}

// ---------------------------------------------------------------------------
// MFMA filter v2: single-product fp16 GEMM, A (128 tokens) in registers,
// B 64-code panels double-buffered in LDS via global_load_lds with XOR
// bank-swizzle applied on the global SOURCE granule (LDS dest linear).
// s~ = b - acc/1024; running-min + margin candidate collection (R6 logic).
// ---------------------------------------------------------------------------
__global__ __launch_bounds__(256, 2) void k_mfma(
    const ushort* __restrict__ zf, const ushort* __restrict__ ef,
    const float* __restrict__ b, int* __restrict__ gcnt,
    ushort* __restrict__ gcand) {
  extern __shared__ char sm[];
  // [0, 65536): B double buffer (2 x 32 KB)
  int*    s_cnt  = (int*)(sm + 65536);    // 128 ints
  ushort* s_idx  = (ushort*)(sm + 66048); // 128*16
  float*  s_val  = (float*)(sm + 70144);  // 128*16
  float*  s_rmin = (float*)(sm + 78336);  // 128 floats (end 78848)

  const int tid = threadIdx.x;
  const int wv  = tid >> 6;
  const int l   = tid & 63;
  const int c16 = l & 15;
  const int kb  = l >> 4;
  const int tokBase = blockIdx.x * 128 + wv * 32;

  if (tid < 128) s_cnt[tid] = 0;

  // A fragments: 2 token-groups x 8 k-chunks, resident in VGPRs
  half8 Az[2][8];
#pragma unroll
  for (int tg = 0; tg < 2; ++tg) {
    const ushort* za = zf + (size_t)(tokBase + tg * 16 + c16) * E_DIM + kb * 8;
#pragma unroll
    for (int kk = 0; kk < 8; ++kk)
      Az[tg][kk] = *(const half8*)(za + kk * 32);
  }

  // prologue: stage panel 0 into buffer 0 (src granule pre-swizzled)
#pragma unroll
  for (int i = 0; i < 8; ++i) {
    const int g = i * 256 + tid;
    const int row = g >> 5, slot = g & 31;
    const int sg = (row << 5) | (slot ^ (row & 7));
    gload_lds16(ef + sg * 8, sm + g * 16);
  }
  __syncthreads();

  float runmin[2][4];
#pragma unroll
  for (int tg = 0; tg < 2; ++tg)
#pragma unroll
    for (int r = 0; r < 4; ++r) runmin[tg][r] = FLT_MAX;

  for (int ct = 0; ct < 32; ++ct) {
    const int cur = ct & 1;
    if (ct + 1 < 32) {
      const ushort* panel = ef + (size_t)(ct + 1) * (64 * E_DIM);
      char* dst = sm + (cur ^ 1) * 32768;
#pragma unroll
      for (int i = 0; i < 8; ++i) {
        const int g = i * 256 + tid;
        const int row = g >> 5, slot = g & 31;
        const int sg = (row << 5) | (slot ^ (row & 7));
        gload_lds16(panel + sg * 8, dst + g * 16);
      }
    }
    float bc[4];
#pragma unroll
    for (int cg = 0; cg < 4; ++cg) bc[cg] = b[ct * 64 + cg * 16 + c16];

    f32x4 acc[2][4];
#pragma unroll
    for (int tg = 0; tg < 2; ++tg)
#pragma unroll
      for (int cg = 0; cg < 4; ++cg) acc[tg][cg] = (f32x4){0.f, 0.f, 0.f, 0.f};

    const char* lb = sm + cur * 32768;
#pragma unroll
    for (int kk = 0; kk < 8; ++kk) {
      half8 Bf[4];
#pragma unroll
      for (int cg = 0; cg < 4; ++cg) {
        const int row = cg * 16 + c16;
        const int slot = ((kk << 2) | kb) ^ (c16 & 7);
        Bf[cg] = *(const half8*)(lb + (((row << 5) | slot) << 4));
      }
#pragma unroll
      for (int tg = 0; tg < 2; ++tg)
#pragma unroll
        for (int cg = 0; cg < 4; ++cg)
          acc[tg][cg] = __builtin_amdgcn_mfma_f32_16x16x32_f16(
              Az[tg][kk], Bf[cg], acc[tg][cg], 0, 0, 0);
    }

    // epilogue: s~ = b - acc/1024, running min + candidate collect
#pragma unroll
    for (int tg = 0; tg < 2; ++tg) {
      float sv[4][4];
#pragma unroll
      for (int cg = 0; cg < 4; ++cg)
#pragma unroll
        for (int r = 0; r < 4; ++r)
          sv[cg][r] = __fmaf_rn(acc[tg][cg][r], -0.0009765625f, bc[cg]);
      float tmin[4];
#pragma unroll
      for (int r = 0; r < 4; ++r)
        tmin[r] = fminf(fminf(sv[0][r], sv[1][r]), fminf(sv[2][r], sv[3][r]));
#pragma unroll
      for (int m = 1; m < 16; m <<= 1)
#pragma unroll
        for (int r = 0; r < 4; ++r)
          tmin[r] = fminf(tmin[r], __shfl_xor(tmin[r], m, 64));
      float thr[4];
      bool anyc = false;
#pragma unroll
      for (int r = 0; r < 4; ++r) {
        runmin[tg][r] = fminf(runmin[tg][r], tmin[r]);
        thr[r] = runmin[tg][r] + MGN;
      }
#pragma unroll
      for (int cg = 0; cg < 4; ++cg)
#pragma unroll
        for (int r = 0; r < 4; ++r) anyc |= (sv[cg][r] <= thr[r]);
      if (__any(anyc)) {
#pragma unroll
        for (int cg = 0; cg < 4; ++cg)
#pragma unroll
          for (int r = 0; r < 4; ++r)
            if (sv[cg][r] <= thr[r]) {
              const int tokl = wv * 32 + tg * 16 + kb * 4 + r;
              const int p = atomicAdd(&s_cnt[tokl], 1);
              if (p < CMAX) {
                s_idx[tokl * CMAX + p] = (ushort)(ct * 64 + cg * 16 + c16);
                s_val[tokl * CMAX + p] = sv[cg][r];
              }
            }
      }
    }
    __syncthreads();
  }

  if (c16 == 0) {
#pragma unroll
    for (int tg = 0; tg < 2; ++tg)
#pragma unroll
      for (int r = 0; r < 4; ++r)
        s_rmin[wv * 32 + tg * 16 + kb * 4 + r] = runmin[tg][r];
  }
  __syncthreads();

  if (tid < 128) {
    const int t = blockIdx.x * 128 + tid;
    const int cnt = s_cnt[tid];
    if (cnt > CMAX) {
      gcnt[t] = 1000;  // overflow sentinel -> full-scan fallback
    } else {
      const float thr = s_rmin[tid] + MGN;
      int nk = 0;
      for (int p = 0; p < cnt; ++p)
        if (s_val[tid * CMAX + p] <= thr)
          gcand[(size_t)t * CMAX + nk++] = s_idx[tid * CMAX + p];
      gcnt[t] = nk;
    }
  }
}

// exact chain re-evaluation of candidates, lexicographic (D, idx) pick
__global__ __launch_bounds__(256) void k_refine(
    const float* __restrict__ z, const float* __restrict__ E,
    const float* __restrict__ a, const float* __restrict__ b,
    const int* __restrict__ gcnt, const ushort* __restrict__ gcand,
    int* __restrict__ idxF, float* __restrict__ out_idx) {
  const int t = blockIdx.x * 256 + threadIdx.x;
  if (t >= N_TOK) return;
  const int cnt = gcnt[t];
  if (cnt > CMAX) return;  // fallback kernel handles
  int bestj;
  if (cnt == 1) {
    bestj = gcand[(size_t)t * CMAX];
  } else {
    float bv = FLT_MAX;
    int bj = 1 << 30;
    const float* zp = z + (size_t)t * E_DIM;
    for (int p = 0; p < cnt; ++p) {
      const int c = gcand[(size_t)t * CMAX + p];
      const float m = chain_m(zp, E + (size_t)c * E_DIM);
      const float D = __fsub_rn(__fadd_rn(a[t], b[c]), __fmul_rn(2.0f, m));
      if (D < bv || (D == bv && c < bj)) { bv = D; bj = c; }
    }
    bestj = bj;
  }
  idxF[t] = bestj;
  out_idx[t] = (float)bestj;
}

// cooperative full scan for overflow tokens (rare)
__global__ __launch_bounds__(256) void k_fallback(
    const float* __restrict__ z, const float* __restrict__ E,
    const float* __restrict__ a, const float* __restrict__ b,
    const int* __restrict__ gcnt, int* __restrict__ idxF,
    float* __restrict__ out_idx) {
  __shared__ float rv[256];
  __shared__ int ri[256];
  const int t0 = blockIdx.x * 64;
  for (int t = t0; t < t0 + 64; ++t) {
    if (gcnt[t] <= CMAX) continue;  // uniform across block
    const float* zp = z + (size_t)t * E_DIM;
    float bv = FLT_MAX;
    int bj = 1 << 30;
    for (int c = threadIdx.x; c < N_E; c += 256) {
      const float m = chain_m(zp, E + (size_t)c * E_DIM);
      const float D = __fsub_rn(__fadd_rn(a[t], b[c]), __fmul_rn(2.0f, m));
      if (D < bv || (D == bv && c < bj)) { bv = D; bj = c; }
    }
    rv[threadIdx.x] = bv;
    ri[threadIdx.x] = bj;
    __syncthreads();
    for (int s = 128; s; s >>= 1) {
      if (threadIdx.x < s) {
        const float ov = rv[threadIdx.x + s];
        const int oj = ri[threadIdx.x + s];
        if (ov < rv[threadIdx.x] ||
            (ov == rv[threadIdx.x] && oj < ri[threadIdx.x])) {
          rv[threadIdx.x] = ov;
          ri[threadIdx.x] = oj;
        }
      }
      __syncthreads();
    }
    if (threadIdx.x == 0) { idxF[t] = ri[0]; out_idx[t] = (float)ri[0]; }
    __syncthreads();
  }
}

// gather z_q, write z_q_st = fl(z + fl(zq - z)), accumulate f64 loss partials
__global__ __launch_bounds__(256) void k_gather(
    const float* __restrict__ z, const float* __restrict__ E,
    const int* __restrict__ idxF, float* __restrict__ out0,
    double* __restrict__ lossPart) {
  double ls = 0.0;
  const int NU = N_TOK * (E_DIM / 4);
  for (int u = blockIdx.x * 256 + threadIdx.x; u < NU; u += 2048 * 256) {
    const int tok = u >> 6;
    const int d4 = (u & 63) * 4;
    const int c = idxF[tok];
    const float4 zq = *(const float4*)&E[(size_t)c * E_DIM + d4];
    const float4 zv = *(const float4*)&z[(size_t)tok * E_DIM + d4];
    float4 o;
    o.x = __fadd_rn(zv.x, __fsub_rn(zq.x, zv.x));
    o.y = __fadd_rn(zv.y, __fsub_rn(zq.y, zv.y));
    o.z = __fadd_rn(zv.z, __fsub_rn(zq.z, zv.z));
    o.w = __fadd_rn(zv.w, __fsub_rn(zq.w, zv.w));
    *(float4*)&out0[(size_t)u * 4] = o;
    double dx;
    dx = (double)zq.x - (double)zv.x; ls += dx * dx;
    dx = (double)zq.y - (double)zv.y; ls += dx * dx;
    dx = (double)zq.z - (double)zv.z; ls += dx * dx;
    dx = (double)zq.w - (double)zv.w; ls += dx * dx;
  }
  __shared__ double red[256];
  red[threadIdx.x] = ls;
  __syncthreads();
  for (int s = 128; s; s >>= 1) {
    if (threadIdx.x < s) red[threadIdx.x] += red[threadIdx.x + s];
    __syncthreads();
  }
  if (threadIdx.x == 0) lossPart[blockIdx.x] = red[0];
}

__global__ __launch_bounds__(256) void k_hist(const int* __restrict__ idxF,
                                              int* __restrict__ counts) {
  const int t = blockIdx.x * 256 + threadIdx.x;
  atomicAdd(&counts[idxF[t]], 1);
}

__global__ __launch_bounds__(256) void k_final(
    const double* __restrict__ lossPart, const int* __restrict__ counts,
    float* __restrict__ outLoss, float* __restrict__ outPerp) {
  __shared__ double rs[256], rh[256];
  double s = 0.0, h = 0.0;
  for (int j = threadIdx.x; j < 2048; j += 256) s += lossPart[j];
  for (int j = threadIdx.x; j < N_E; j += 256) {
    const double p = (double)counts[j] * (1.0 / (double)N_TOK);
    h -= p * log(p + 1e-10);
  }
  rs[threadIdx.x] = s;
  rh[threadIdx.x] = h;
  __syncthreads();
  for (int m = 128; m; m >>= 1) {
    if (threadIdx.x < m) {
      rs[threadIdx.x] += rs[threadIdx.x + m];
      rh[threadIdx.x] += rh[threadIdx.x + m];
    }
    __syncthreads();
  }
  if (threadIdx.x == 0) {
    outLoss[0] = (float)((1.0 + BETA) * rs[0] / (double)((size_t)N_TOK * E_DIM));
    outPerp[0] = (float)exp(rh[0]);
  }
}

extern "C" void kernel_launch(void* const* d_in, const int* in_sizes, int n_in,
                              void* d_out, int out_size, void* d_ws, size_t ws_size,
                              hipStream_t stream) {
  const float* z = (const float*)d_in[0];
  const float* E = (const float*)d_in[1];

  float* out0 = (float*)d_out;                       // z_q_st [65536*256]
  float* outLoss = out0 + (size_t)N_TOK * E_DIM;
  float* outPerp = outLoss + 1;
  float* outIdx = outPerp + 1;                       // idx as float [65536]

  char* ws = (char*)d_ws;
  double* lossPart = (double*)(ws + WS_LOSSPART);
  float* a = (float*)(ws + WS_A);
  float* b = (float*)(ws + WS_B);
  int* idxF = (int*)(ws + WS_IDXF);
  int* counts = (int*)(ws + WS_COUNTS);
  int* gcnt = (int*)(ws + WS_CCNT);
  ushort* gcand = (ushort*)(ws + WS_CAND);

  // fp16 operands live in the z_q_st output region (33.5 MB + 1 MB < 64 MB);
  // k_gather fully overwrites that region afterwards. Deterministic per call.
  ushort* zf = (ushort*)out0;
  ushort* ef = zf + (size_t)N_TOK * E_DIM;

  (void)hipFuncSetAttribute(reinterpret_cast<const void*>(k_mfma),
                            hipFuncAttributeMaxDynamicSharedMemorySize, 78848);

  hipLaunchKernelGGL(k_zero, dim3(8), dim3(256), 0, stream, counts);
  hipLaunchKernelGGL(k_ab, dim3((N_TOK + N_E) / 256), dim3(256), 0, stream,
                     z, E, a, b);
  hipLaunchKernelGGL(k_cvt, dim3((N_TOK * E_DIM + N_E * E_DIM) / 8 / 256),
                     dim3(256), 0, stream, z, E, zf, ef);
  hipLaunchKernelGGL(k_mfma, dim3(N_TOK / 128), dim3(256), 78848, stream,
                     zf, ef, b, gcnt, gcand);
  hipLaunchKernelGGL(k_refine, dim3(N_TOK / 256), dim3(256), 0, stream,
                     z, E, a, b, gcnt, gcand, idxF, outIdx);
  hipLaunchKernelGGL(k_fallback, dim3(N_TOK / 64), dim3(256), 0, stream,
                     z, E, a, b, gcnt, idxF, outIdx);
  hipLaunchKernelGGL(k_gather, dim3(2048), dim3(256), 0, stream,
                     z, E, idxF, out0, lossPart);
  hipLaunchKernelGGL(k_hist, dim3(N_TOK / 256), dim3(256), 0, stream, idxF, counts);
  hipLaunchKernelGGL(k_final, dim3(1), dim3(256), 0, stream,
                     lossPart, counts, outLoss, outPerp);
}

// Round 8
// 304.884 us; speedup vs baseline: 3.6343x; 1.0760x over previous
//
#include <hip/hip_runtime.h>
#include <cfloat>
#include <cmath>
#include <cstdint>

#define N_TOK 65536
#define N_E   2048
#define E_DIM 256
#define BETA  0.25

#define MGN 8e-4f     // capture margin; worst-case requirement ~6e-4
#define CMAX 16

// ws layout (bytes)
#define WS_LOSSPART 0          // double[2048]    -> 16384
#define WS_A        16384      // float[65536]    -> 278528
#define WS_B        278528     // float[2048]     -> 286720
#define WS_IDXF     286720     // int[65536]      -> 548864
#define WS_COUNTS   548864     // int[2048]       -> 557056
#define WS_CCNT     2654208    // int[65536]      -> 2916352
#define WS_CAND     2916352    // ushort[65536*16]-> 5013504

typedef __attribute__((ext_vector_type(8))) _Float16 half8;
typedef __attribute__((ext_vector_type(4))) float f32x4;

__device__ __forceinline__ ushort f2h(float f) {
  union { _Float16 h; ushort u; } c;
  c.h = (_Float16)f;   // RNE
  return c.u;
}

__device__ __forceinline__ void gload_lds16(const void* g, void* l) {
  __builtin_amdgcn_global_load_lds(
      (const __attribute__((address_space(1))) unsigned int*)(g),
      (__attribute__((address_space(3))) unsigned int*)(l), 16, 0, 0);
}

__device__ __forceinline__ float4 f4add(float4 x, float4 y) {
  float4 r;
  r.x = __fadd_rn(x.x, y.x); r.y = __fadd_rn(x.y, y.y);
  r.z = __fadd_rn(x.z, y.z); r.w = __fadd_rn(x.w, y.w);
  return r;
}

// exact sequential fused-FMA chain (verified bit-exact vs numpy sgemm, R3)
__device__ __forceinline__ float chain_m(const float* __restrict__ zp,
                                         const float* __restrict__ ep) {
  float acc = 0.f;
  for (int k = 0; k < E_DIM; k += 4) {
    const float4 zz = *(const float4*)(zp + k);
    const float4 ee = *(const float4*)(ep + k);
    acc = __fmaf_rn(zz.x, ee.x, acc);
    acc = __fmaf_rn(zz.y, ee.y, acc);
    acc = __fmaf_rn(zz.z, ee.z, acc);
    acc = __fmaf_rn(zz.w, ee.w, acc);
  }
  return acc;
}

// ---------------------------------------------------------------------------
// k_prep: fused (zero counts) + (fp16 convert: z raw, E x2048) + (numpy f32
// pairwise sum-of-squares, verified bit-exact in R3). One thread per 128-float
// half-row; float4 loads; componentwise tree == scalar tree exactly:
// colsum4[c4][j] = lane[4*c4+j]; u0=c0+c2, u1=c1+c3, v=u0+u1,
// w0=v.x+v.z, w1=v.y+v.w, blk=w0+w1; pair-combine via shfl_xor(1).
// ---------------------------------------------------------------------------
__global__ __launch_bounds__(256) void k_prep(
    const float* __restrict__ z, const float* __restrict__ E,
    ushort* __restrict__ zf, ushort* __restrict__ ef,
    float* __restrict__ a, float* __restrict__ b, int* __restrict__ counts) {
  if (blockIdx.x == 0) {
    for (int i = threadIdx.x; i < N_E; i += 256) counts[i] = 0;
  }
  const int hr = blockIdx.x * 256 + threadIdx.x;
  const int NZH = N_TOK * 2;                 // 131072 z half-rows
  const bool isZ = hr < NZH;
  const int lr = isZ ? hr : hr - NZH;
  if (!isZ && lr >= N_E * 2) return;
  const int row = lr >> 1, h = lr & 1;
  const float* src = (isZ ? z + (size_t)row * E_DIM
                          : E + (size_t)row * E_DIM) + h * 128;
  ushort* dst = (isZ ? zf + (size_t)row * E_DIM
                     : ef + (size_t)row * E_DIM) + h * 128;
  const float scale = isZ ? 1.0f : 2048.0f;

  float4 colsum[4];
#pragma unroll
  for (int c4 = 0; c4 < 4; ++c4) {
    float4 q[8];
#pragma unroll
    for (int r = 0; r < 8; ++r) {
      const float4 v = *(const float4*)(src + r * 16 + c4 * 4);
      ushort4 o;
      o.x = f2h(v.x * scale); o.y = f2h(v.y * scale);
      o.z = f2h(v.z * scale); o.w = f2h(v.w * scale);
      *(ushort4*)(dst + r * 16 + c4 * 4) = o;
      q[r].x = __fmul_rn(v.x, v.x); q[r].y = __fmul_rn(v.y, v.y);
      q[r].z = __fmul_rn(v.z, v.z); q[r].w = __fmul_rn(v.w, v.w);
    }
    const float4 A = f4add(q[0], q[1]);
    const float4 B = f4add(q[2], q[3]);
    const float4 C = f4add(q[4], q[5]);
    const float4 D = f4add(q[6], q[7]);
    colsum[c4] = f4add(f4add(A, B), f4add(C, D));
  }
  const float4 u0 = f4add(colsum[0], colsum[2]);
  const float4 u1 = f4add(colsum[1], colsum[3]);
  const float4 vv = f4add(u0, u1);
  const float w0 = __fadd_rn(vv.x, vv.z);
  const float w1 = __fadd_rn(vv.y, vv.w);
  const float blk = __fadd_rn(w0, w1);

  const float other = __shfl_xor(blk, 1, 64);
  if (h == 0) {
    const float s = __fadd_rn(blk, other);   // blk[0] + blk[1] exact order
    if (isZ) a[row] = s; else b[row] = s;
  }
}

// ---------------------------------------------------------------------------
// MFMA filter v3: 512 threads (8 waves x 16 tokens = 128 tokens/block),
// fp16 single-product GEMM, B panels (64 codes x K=256) double-buffered in
// LDS via global_load_lds (source-granule XOR swizzle, LDS dest linear).
// s~ = b - acc/1024; running-min + margin candidate collection.
// ---------------------------------------------------------------------------
__global__ __launch_bounds__(512, 4) void k_mfma(
    const ushort* __restrict__ zf, const ushort* __restrict__ ef,
    const float* __restrict__ b, int* __restrict__ gcnt,
    ushort* __restrict__ gcand) {
  extern __shared__ char sm[];
  // [0, 65536): B double buffer (2 x 32 KB)
  int*    s_cnt  = (int*)(sm + 65536);    // 128 ints
  ushort* s_idx  = (ushort*)(sm + 66048); // 128*16
  float*  s_val  = (float*)(sm + 70144);  // 128*16
  float*  s_rmin = (float*)(sm + 78336);  // 128 floats (end 78848)

  const int tid = threadIdx.x;
  const int wv  = tid >> 6;      // 0..7
  const int l   = tid & 63;
  const int c16 = l & 15;
  const int kb  = l >> 4;
  const int tokBase = blockIdx.x * 128 + wv * 16;

  if (tid < 128) s_cnt[tid] = 0;

  // A fragments: 16 tokens x K=256 (8 chunks of 32), resident in VGPRs
  half8 Az[8];
  {
    const ushort* za = zf + (size_t)(tokBase + c16) * E_DIM + kb * 8;
#pragma unroll
    for (int kk = 0; kk < 8; ++kk) Az[kk] = *(const half8*)(za + kk * 32);
  }

  // prologue: stage panel 0 into buffer 0 (src granule pre-swizzled)
#pragma unroll
  for (int i = 0; i < 4; ++i) {
    const int g = i * 512 + tid;
    const int row = g >> 5, slot = g & 31;
    const int sg = (row << 5) | (slot ^ (row & 7));
    gload_lds16(ef + sg * 8, sm + g * 16);
  }
  __syncthreads();

  float runmin[4] = {FLT_MAX, FLT_MAX, FLT_MAX, FLT_MAX};

  for (int ct = 0; ct < 32; ++ct) {
    const int cur = ct & 1;
    if (ct + 1 < 32) {
      const ushort* panel = ef + (size_t)(ct + 1) * (64 * E_DIM);
      char* dst = sm + (cur ^ 1) * 32768;
#pragma unroll
      for (int i = 0; i < 4; ++i) {
        const int g = i * 512 + tid;
        const int row = g >> 5, slot = g & 31;
        const int sg = (row << 5) | (slot ^ (row & 7));
        gload_lds16(panel + sg * 8, dst + g * 16);
      }
    }
    float bc[4];
#pragma unroll
    for (int cg = 0; cg < 4; ++cg) bc[cg] = b[ct * 64 + cg * 16 + c16];

    f32x4 acc[4];
#pragma unroll
    for (int cg = 0; cg < 4; ++cg) acc[cg] = (f32x4){0.f, 0.f, 0.f, 0.f};

    const char* lb = sm + cur * 32768;
#pragma unroll
    for (int kk = 0; kk < 8; ++kk) {
      half8 Bf[4];
#pragma unroll
      for (int cg = 0; cg < 4; ++cg) {
        const int row = cg * 16 + c16;
        const int slot = ((kk << 2) | kb) ^ (c16 & 7);
        Bf[cg] = *(const half8*)(lb + (((row << 5) | slot) << 4));
      }
#pragma unroll
      for (int cg = 0; cg < 4; ++cg)
        acc[cg] = __builtin_amdgcn_mfma_f32_16x16x32_f16(
            Az[kk], Bf[cg], acc[cg], 0, 0, 0);
    }

    // epilogue: s~ = b - acc/1024, running min + candidate collect
    float sv[4][4];
#pragma unroll
    for (int cg = 0; cg < 4; ++cg)
#pragma unroll
      for (int r = 0; r < 4; ++r)
        sv[cg][r] = __fmaf_rn(acc[cg][r], -0.0009765625f, bc[cg]);
    float tmin[4];
#pragma unroll
    for (int r = 0; r < 4; ++r)
      tmin[r] = fminf(fminf(sv[0][r], sv[1][r]), fminf(sv[2][r], sv[3][r]));
#pragma unroll
    for (int m = 1; m < 16; m <<= 1)
#pragma unroll
      for (int r = 0; r < 4; ++r)
        tmin[r] = fminf(tmin[r], __shfl_xor(tmin[r], m, 64));
    float thr[4];
    bool anyc = false;
#pragma unroll
    for (int r = 0; r < 4; ++r) {
      runmin[r] = fminf(runmin[r], tmin[r]);
      thr[r] = runmin[r] + MGN;
    }
#pragma unroll
    for (int cg = 0; cg < 4; ++cg)
#pragma unroll
      for (int r = 0; r < 4; ++r) anyc |= (sv[cg][r] <= thr[r]);
    if (__any(anyc)) {
#pragma unroll
      for (int cg = 0; cg < 4; ++cg)
#pragma unroll
        for (int r = 0; r < 4; ++r)
          if (sv[cg][r] <= thr[r]) {
            const int tokl = wv * 16 + kb * 4 + r;
            const int p = atomicAdd(&s_cnt[tokl], 1);
            if (p < CMAX) {
              s_idx[tokl * CMAX + p] = (ushort)(ct * 64 + cg * 16 + c16);
              s_val[tokl * CMAX + p] = sv[cg][r];
            }
          }
    }
    __syncthreads();
  }

  if (c16 == 0) {
#pragma unroll
    for (int r = 0; r < 4; ++r)
      s_rmin[wv * 16 + kb * 4 + r] = runmin[r];
  }
  __syncthreads();

  if (tid < 128) {
    const int t = blockIdx.x * 128 + tid;
    const int cnt = s_cnt[tid];
    if (cnt > CMAX) {
      gcnt[t] = 1000;  // overflow sentinel -> full-scan fallback
    } else {
      const float thr = s_rmin[tid] + MGN;
      int nk = 0;
      for (int p = 0; p < cnt; ++p)
        if (s_val[tid * CMAX + p] <= thr)
          gcand[(size_t)t * CMAX + nk++] = s_idx[tid * CMAX + p];
      gcnt[t] = nk;
    }
  }
}

// exact chain re-evaluation of candidates, lexicographic (D, idx) pick,
// fused histogram
__global__ __launch_bounds__(256) void k_refine(
    const float* __restrict__ z, const float* __restrict__ E,
    const float* __restrict__ a, const float* __restrict__ b,
    const int* __restrict__ gcnt, const ushort* __restrict__ gcand,
    int* __restrict__ idxF, float* __restrict__ out_idx,
    int* __restrict__ counts) {
  const int t = blockIdx.x * 256 + threadIdx.x;
  if (t >= N_TOK) return;
  const int cnt = gcnt[t];
  if (cnt > CMAX) return;  // fallback kernel handles (incl. its histogram)
  int bestj;
  if (cnt == 1) {
    bestj = gcand[(size_t)t * CMAX];
  } else {
    float bv = FLT_MAX;
    int bj = 1 << 30;
    const float* zp = z + (size_t)t * E_DIM;
    for (int p = 0; p < cnt; ++p) {
      const int c = gcand[(size_t)t * CMAX + p];
      const float m = chain_m(zp, E + (size_t)c * E_DIM);
      const float D = __fsub_rn(__fadd_rn(a[t], b[c]), __fmul_rn(2.0f, m));
      if (D < bv || (D == bv && c < bj)) { bv = D; bj = c; }
    }
    bestj = bj;
  }
  idxF[t] = bestj;
  out_idx[t] = (float)bestj;
  atomicAdd(&counts[bestj], 1);
}

// cooperative full scan for overflow tokens (rare), fused histogram
__global__ __launch_bounds__(256) void k_fallback(
    const float* __restrict__ z, const float* __restrict__ E,
    const float* __restrict__ a, const float* __restrict__ b,
    const int* __restrict__ gcnt, int* __restrict__ idxF,
    float* __restrict__ out_idx, int* __restrict__ counts) {
  __shared__ float rv[256];
  __shared__ int ri[256];
  const int t0 = blockIdx.x * 64;
  for (int t = t0; t < t0 + 64; ++t) {
    if (gcnt[t] <= CMAX) continue;  // uniform across block
    const float* zp = z + (size_t)t * E_DIM;
    float bv = FLT_MAX;
    int bj = 1 << 30;
    for (int c = threadIdx.x; c < N_E; c += 256) {
      const float m = chain_m(zp, E + (size_t)c * E_DIM);
      const float D = __fsub_rn(__fadd_rn(a[t], b[c]), __fmul_rn(2.0f, m));
      if (D < bv || (D == bv && c < bj)) { bv = D; bj = c; }
    }
    rv[threadIdx.x] = bv;
    ri[threadIdx.x] = bj;
    __syncthreads();
    for (int s = 128; s; s >>= 1) {
      if (threadIdx.x < s) {
        const float ov = rv[threadIdx.x + s];
        const int oj = ri[threadIdx.x + s];
        if (ov < rv[threadIdx.x] ||
            (ov == rv[threadIdx.x] && oj < ri[threadIdx.x])) {
          rv[threadIdx.x] = ov;
          ri[threadIdx.x] = oj;
        }
      }
      __syncthreads();
    }
    if (threadIdx.x == 0) {
      idxF[t] = ri[0];
      out_idx[t] = (float)ri[0];
      atomicAdd(&counts[ri[0]], 1);
    }
    __syncthreads();
  }
}

// gather z_q, write z_q_st = fl(z + fl(zq - z)), accumulate f64 loss partials
__global__ __launch_bounds__(256) void k_gather(
    const float* __restrict__ z, const float* __restrict__ E,
    const int* __restrict__ idxF, float* __restrict__ out0,
    double* __restrict__ lossPart) {
  double ls = 0.0;
  const int NU = N_TOK * (E_DIM / 4);
  for (int u = blockIdx.x * 256 + threadIdx.x; u < NU; u += 2048 * 256) {
    const int tok = u >> 6;
    const int d4 = (u & 63) * 4;
    const int c = idxF[tok];
    const float4 zq = *(const float4*)&E[(size_t)c * E_DIM + d4];
    const float4 zv = *(const float4*)&z[(size_t)tok * E_DIM + d4];
    float4 o;
    o.x = __fadd_rn(zv.x, __fsub_rn(zq.x, zv.x));
    o.y = __fadd_rn(zv.y, __fsub_rn(zq.y, zv.y));
    o.z = __fadd_rn(zv.z, __fsub_rn(zq.z, zv.z));
    o.w = __fadd_rn(zv.w, __fsub_rn(zq.w, zv.w));
    *(float4*)&out0[(size_t)u * 4] = o;
    double dx;
    dx = (double)zq.x - (double)zv.x; ls += dx * dx;
    dx = (double)zq.y - (double)zv.y; ls += dx * dx;
    dx = (double)zq.z - (double)zv.z; ls += dx * dx;
    dx = (double)zq.w - (double)zv.w; ls += dx * dx;
  }
  __shared__ double red[256];
  red[threadIdx.x] = ls;
  __syncthreads();
  for (int s = 128; s; s >>= 1) {
    if (threadIdx.x < s) red[threadIdx.x] += red[threadIdx.x + s];
    __syncthreads();
  }
  if (threadIdx.x == 0) lossPart[blockIdx.x] = red[0];
}

__global__ __launch_bounds__(256) void k_final(
    const double* __restrict__ lossPart, const int* __restrict__ counts,
    float* __restrict__ outLoss, float* __restrict__ outPerp) {
  __shared__ double rs[256], rh[256];
  double s = 0.0, h = 0.0;
  for (int j = threadIdx.x; j < 2048; j += 256) s += lossPart[j];
  for (int j = threadIdx.x; j < N_E; j += 256) {
    const double p = (double)counts[j] * (1.0 / (double)N_TOK);
    h -= p * log(p + 1e-10);
  }
  rs[threadIdx.x] = s;
  rh[threadIdx.x] = h;
  __syncthreads();
  for (int m = 128; m; m >>= 1) {
    if (threadIdx.x < m) {
      rs[threadIdx.x] += rs[threadIdx.x + m];
      rh[threadIdx.x] += rh[threadIdx.x + m];
    }
    __syncthreads();
  }
  if (threadIdx.x == 0) {
    outLoss[0] = (float)((1.0 + BETA) * rs[0] / (double)((size_t)N_TOK * E_DIM));
    outPerp[0] = (float)exp(rh[0]);
  }
}

extern "C" void kernel_launch(void* const* d_in, const int* in_sizes, int n_in,
                              void* d_out, int out_size, void* d_ws, size_t ws_size,
                              hipStream_t stream) {
  const float* z = (const float*)d_in[0];
  const float* E = (const float*)d_in[1];

  float* out0 = (float*)d_out;                       // z_q_st [65536*256]
  float* outLoss = out0 + (size_t)N_TOK * E_DIM;
  float* outPerp = outLoss + 1;
  float* outIdx = outPerp + 1;                       // idx as float [65536]

  char* ws = (char*)d_ws;
  double* lossPart = (double*)(ws + WS_LOSSPART);
  float* a = (float*)(ws + WS_A);
  float* b = (float*)(ws + WS_B);
  int* idxF = (int*)(ws + WS_IDXF);
  int* counts = (int*)(ws + WS_COUNTS);
  int* gcnt = (int*)(ws + WS_CCNT);
  ushort* gcand = (ushort*)(ws + WS_CAND);

  // fp16 operands live in the z_q_st output region (34.6 MB < 64 MB);
  // k_gather fully overwrites that region afterwards. Deterministic per call.
  ushort* zf = (ushort*)out0;
  ushort* ef = zf + (size_t)N_TOK * E_DIM;

  (void)hipFuncSetAttribute(reinterpret_cast<const void*>(k_mfma),
                            hipFuncAttributeMaxDynamicSharedMemorySize, 78848);

  hipLaunchKernelGGL(k_prep, dim3((N_TOK * 2 + N_E * 2) / 256), dim3(256), 0,
                     stream, z, E, zf, ef, a, b, counts);
  hipLaunchKernelGGL(k_mfma, dim3(N_TOK / 128), dim3(512), 78848, stream,
                     zf, ef, b, gcnt, gcand);
  hipLaunchKernelGGL(k_refine, dim3(N_TOK / 256), dim3(256), 0, stream,
                     z, E, a, b, gcnt, gcand, idxF, outIdx, counts);
  hipLaunchKernelGGL(k_fallback, dim3(N_TOK / 64), dim3(256), 0, stream,
                     z, E, a, b, gcnt, idxF, outIdx, counts);
  hipLaunchKernelGGL(k_gather, dim3(2048), dim3(256), 0, stream,
                     z, E, idxF, out0, lossPart);
  hipLaunchKernelGGL(k_final, dim3(1), dim3(256), 0, stream,
                     lossPart, counts, outLoss, outPerp);
}